// Round 4
// baseline (453.484 us; speedup 1.0000x reference)
//
#include <hip/hip_runtime.h>
#include <hip/hip_bf16.h>
#include <math.h>

// R4: same algorithm as R2/R3 (never measured — broker died twice).
// Hedge: hipMemsetAsync(d_ws) replaced by a zeroing kernel.

#define N_NODES 50000
#define N_EDGES 800000
#define DIM 64
#define HID 64

typedef __bf16 bf16_t;
typedef __bf16 bf16x8 __attribute__((ext_vector_type(8)));
typedef float f32x4 __attribute__((ext_vector_type(4)));

__device__ __forceinline__ float silu_f(float x) {
    return x / (1.f + __expf(-x));
}

__device__ __forceinline__ f32x4 mfma16(bf16x8 a, bf16x8 b, f32x4 c) {
    return __builtin_amdgcn_mfma_f32_16x16x32_bf16(a, b, c, 0, 0, 0);
}

// load 8 consecutive fp32 (32B-aligned) and convert to a bf16 A/B fragment
__device__ __forceinline__ bf16x8 cvt8(const float* __restrict__ p) {
    f32x4 u0 = *(const f32x4*)p;
    f32x4 u1 = *(const f32x4*)(p + 4);
    bf16x8 r;
    r[0] = (bf16_t)u0[0]; r[1] = (bf16_t)u0[1]; r[2] = (bf16_t)u0[2]; r[3] = (bf16_t)u0[3];
    r[4] = (bf16_t)u1[0]; r[5] = (bf16_t)u1[1]; r[6] = (bf16_t)u1[2]; r[7] = (bf16_t)u1[3];
    return r;
}

// ---------------------------------------------------------------------------
// Zero the fp32 aggregation workspace (graph-capture-safe, no memset API)
// ---------------------------------------------------------------------------
__global__ __launch_bounds__(256) void zero_kernel(float* __restrict__ p, int n4)
{
    int i = blockIdx.x * 256 + threadIdx.x;
    if (i < n4) {
        f32x4 z = {0.f, 0.f, 0.f, 0.f};
        *(f32x4*)(p + (size_t)i * 4) = z;
    }
}

// ---------------------------------------------------------------------------
// Edge kernel: per 16-edge wave tile:
//   mij = silu(silu([h[row]||h[col]] @ eW1 + eb1) @ eW2 + eb2)
//   write mij (fp32) + atomic scatter-add fp32 into agg[row]
// ---------------------------------------------------------------------------
__global__ __launch_bounds__(256) void edge_kernel(
    const float* __restrict__ h,
    const int* __restrict__ ei,
    const float* __restrict__ eW1, const float* __restrict__ eb1,
    const float* __restrict__ eW2, const float* __restrict__ eb2,
    float* __restrict__ mij_out,
    float* __restrict__ agg)
{
    __shared__ __align__(16) bf16_t sB1[64][136];   // eW1^T [n][k], k<128
    __shared__ __align__(16) bf16_t sB2[64][72];    // eW2^T [n][k], k<64
    __shared__ __align__(16) bf16_t sHid[4][16][72];
    __shared__ float sb1[64], sb2[64];

    const int tid = threadIdx.x;
    for (int idx = tid; idx < 128 * 64; idx += 256) {
        int k = idx >> 6, n = idx & 63;
        sB1[n][k] = (bf16_t)eW1[idx];
    }
    for (int idx = tid; idx < 64 * 64; idx += 256) {
        int k = idx >> 6, n = idx & 63;
        sB2[n][k] = (bf16_t)eW2[idx];
    }
    if (tid < 64) { sb1[tid] = eb1[tid]; sb2[tid] = eb2[tid]; }
    __syncthreads();

    const int lane = tid & 63, wave = tid >> 6;
    const int m = lane & 15, quad = lane >> 4;
    const int e0 = (blockIdx.x * 4 + wave) * 16;
    const int e = e0 + m;
    const int nrow = ei[e];
    const int ncol = ei[N_EDGES + e];
    const float* ra = h + (size_t)nrow * DIM;
    const float* rb = h + (size_t)ncol * DIM;

    const f32x4 z = {0.f, 0.f, 0.f, 0.f};
    f32x4 acc[4] = {z, z, z, z};
    #pragma unroll
    for (int ks = 0; ks < 4; ++ks) {
        const int k0 = ks * 32 + quad * 8;
        const float* src = (k0 < 64) ? (ra + k0) : (rb + (k0 - 64));
        bf16x8 a = cvt8(src);
        #pragma unroll
        for (int nt = 0; nt < 4; ++nt) {
            bf16x8 b = *(const bf16x8*)&sB1[nt * 16 + m][k0];
            acc[nt] = mfma16(a, b, acc[nt]);
        }
    }

    #pragma unroll
    for (int nt = 0; nt < 4; ++nt) {
        #pragma unroll
        for (int rr = 0; rr < 4; ++rr) {
            int row = quad * 4 + rr;
            int col = nt * 16 + m;
            sHid[wave][row][col] = (bf16_t)silu_f(acc[nt][rr] + sb1[col]);
        }
    }
    __syncthreads();

    f32x4 acc2[4] = {z, z, z, z};
    #pragma unroll
    for (int ks = 0; ks < 2; ++ks) {
        const int k0 = ks * 32 + quad * 8;
        bf16x8 a = *(const bf16x8*)&sHid[wave][m][k0];
        #pragma unroll
        for (int nt = 0; nt < 4; ++nt) {
            bf16x8 b = *(const bf16x8*)&sB2[nt * 16 + m][k0];
            acc2[nt] = mfma16(a, b, acc2[nt]);
        }
    }

    #pragma unroll
    for (int nt = 0; nt < 4; ++nt) {
        #pragma unroll
        for (int rr = 0; rr < 4; ++rr) {
            int row = quad * 4 + rr;
            int col = nt * 16 + m;
            float v = silu_f(acc2[nt][rr] + sb2[col]);
            int ee = e0 + row;
            mij_out[(size_t)ee * HID + col] = v;
            int dst = __shfl(nrow, row);   // ei[0][e0+row], held by lane 'row'
            unsafeAtomicAdd(&agg[dst * HID + col], v);
        }
    }
}

// ---------------------------------------------------------------------------
// Node kernel: per 16-node wave tile:
//   a  = [h, agg/100]                       (K=128)
//   t  = silu(a @ qW1 + qb1); q_in = t @ qW2 + qb2   (3 cols, scalar lanes)
//   q_out = 3-qubit statevector circuit (fp32, 1 lane per node)
//   a2 = [a, q_out] (K=131, padded to 160)
//   out = h + silu(a2 @ pW1 + pb1) @ pW2 + pb2
// ---------------------------------------------------------------------------
__global__ __launch_bounds__(256) void node_kernel(
    const float* __restrict__ h, const float* __restrict__ agg,
    const float* __restrict__ qW1, const float* __restrict__ qb1,
    const float* __restrict__ qW2, const float* __restrict__ qb2,
    const float* __restrict__ pW1, const float* __restrict__ pb1,
    const float* __restrict__ pW2, const float* __restrict__ pb2,
    const float* __restrict__ al_p, const float* __restrict__ be_p,
    const float* __restrict__ ga_p, const float* __restrict__ de_p,
    const float* __restrict__ lam_p,
    float* __restrict__ out)
{
    __shared__ __align__(16) bf16_t sQ1[64][136];   // qW1^T [n][k], k<128
    __shared__ __align__(16) bf16_t sP1[64][168];   // pW1^T [n][k], k<160 (zero pad k>=131)
    __shared__ __align__(16) bf16_t sP2[64][72];    // pW2^T
    __shared__ __align__(16) bf16_t sHid[4][16][72];
    __shared__ float sQ2[192];                      // qW2 [k][c] row-major, fp32
    __shared__ float sqb1[64], spb1[64], spb2[64], sqb2[3];
    __shared__ float sQout[4][16][3];

    const int tid = threadIdx.x;
    for (int idx = tid; idx < 128 * 64; idx += 256) { int k = idx >> 6, n = idx & 63; sQ1[n][k] = (bf16_t)qW1[idx]; }
    for (int idx = tid; idx < 131 * 64; idx += 256) { int k = idx >> 6, n = idx & 63; sP1[n][k] = (bf16_t)pW1[idx]; }
    for (int idx = tid; idx < 29 * 64; idx += 256) { int k = 131 + (idx >> 6), n = idx & 63; sP1[n][k] = (bf16_t)0.f; }
    for (int idx = tid; idx < 64 * 64; idx += 256) { int k = idx >> 6, n = idx & 63; sP2[n][k] = (bf16_t)pW2[idx]; }
    if (tid < 192) sQ2[tid] = qW2[tid];
    if (tid < 64) { sqb1[tid] = qb1[tid]; spb1[tid] = pb1[tid]; spb2[tid] = pb2[tid]; }
    if (tid < 3) sqb2[tid] = qb2[tid];
    __syncthreads();

    const int lane = tid & 63, wave = tid >> 6;
    const int m = lane & 15, quad = lane >> 4;
    const int n0 = (blockIdx.x * 4 + wave) * 16;
    const int nm = min(n0 + m, N_NODES - 1);
    const float* hrow = h + (size_t)nm * DIM;
    const float* grow = agg + (size_t)nm * HID;

    const f32x4 z = {0.f, 0.f, 0.f, 0.f};

    // ---- t = silu([h, agg/100] @ qW1 + qb1)
    f32x4 acc[4] = {z, z, z, z};
    #pragma unroll
    for (int ks = 0; ks < 4; ++ks) {
        const int k0 = ks * 32 + quad * 8;
        bf16x8 a;
        if (k0 < 64) {
            a = cvt8(hrow + k0);
        } else {
            const float* g = grow + (k0 - 64);
            f32x4 u0 = *(const f32x4*)g;
            f32x4 u1 = *(const f32x4*)(g + 4);
            #pragma unroll
            for (int j = 0; j < 4; ++j) { a[j] = (bf16_t)(u0[j] * 0.01f); a[4 + j] = (bf16_t)(u1[j] * 0.01f); }
        }
        #pragma unroll
        for (int nt = 0; nt < 4; ++nt) {
            bf16x8 b = *(const bf16x8*)&sQ1[nt * 16 + m][k0];
            acc[nt] = mfma16(a, b, acc[nt]);
        }
    }
    #pragma unroll
    for (int nt = 0; nt < 4; ++nt) {
        #pragma unroll
        for (int rr = 0; rr < 4; ++rr) {
            int row = quad * 4 + rr, col = nt * 16 + m;
            sHid[wave][row][col] = (bf16_t)silu_f(acc[nt][rr] + sqb1[col]);
        }
    }
    __syncthreads();

    // ---- q_in (3 dots of 64) + quantum circuit, one lane per node
    const float al = al_p[0], be = be_p[0];
    const float ga = ga_p[0], de = de_p[0];

    if (lane < 16) {
        float qin[3];
        #pragma unroll
        for (int c = 0; c < 3; ++c) {
            float s = sqb2[c];
            for (int k = 0; k < 64; ++k)
                s += (float)sHid[wave][lane][k] * sQ2[k * 3 + c];
            qin[c] = s;
        }
        float re[8], im[8];
        float cc[3], ssn[3];
        #pragma unroll
        for (int q = 0; q < 3; ++q) {
            float th = 0.5f * qin[q] * al;
            cc[q] = cosf(th); ssn[q] = sinf(th);
        }
        #pragma unroll
        for (int i = 0; i < 8; ++i) {   // RY data-encoding layer on |000>
            float v0 = (i & 4) ? ssn[0] : cc[0];
            float v1 = (i & 2) ? ssn[1] : cc[1];
            float v2 = (i & 1) ? ssn[2] : cc[2];
            re[i] = v0 * v1 * v2; im[i] = 0.f;
        }
        // IsingZZ coupling (diagonal phases)
        float phi01 = ga * (lam_p[1] + lam_p[3]) * 0.5f;
        float phi02 = ga * (lam_p[2] + lam_p[6]) * 0.5f;
        float phi12 = ga * (lam_p[5] + lam_p[7]) * 0.5f;
        #pragma unroll
        for (int i = 0; i < 8; ++i) {
            float z0 = (i & 4) ? -1.f : 1.f;
            float z1 = (i & 2) ? -1.f : 1.f;
            float z2 = (i & 1) ? -1.f : 1.f;
            float th = -0.5f * (phi01 * z0 * z1 + phi02 * z0 * z2 + phi12 * z1 * z2);
            float ct = cosf(th), st = sinf(th);
            float r = re[i], iM = im[i];
            re[i] = r * ct - iM * st;
            im[i] = r * st + iM * ct;
        }
        float cb = cosf(0.5f * be), sb = sinf(0.5f * be);
        auto rx = [&](int q) {
            int msk = 4 >> q;
            #pragma unroll
            for (int i = 0; i < 8; ++i) {
                if (i & msk) continue;
                int j = i | msk;
                float r0 = re[i], i0 = im[i], r1 = re[j], i1 = im[j];
                re[i] = cb * r0 + sb * i1;
                im[i] = cb * i0 - sb * r1;
                re[j] = sb * i0 + cb * r1;
                im[j] = -sb * r0 + cb * i1;
            }
        };
        auto hgate = [&](int q) {
            const float inv = 0.70710678f;
            int msk = 4 >> q;
            #pragma unroll
            for (int i = 0; i < 8; ++i) {
                if (i & msk) continue;
                int j = i | msk;
                float r0 = re[i], i0 = im[i], r1 = re[j], i1 = im[j];
                re[i] = (r0 + r1) * inv; im[i] = (i0 + i1) * inv;
                re[j] = (r0 - r1) * inv; im[j] = (i0 - i1) * inv;
            }
        };
        auto rzg = [&](int q, float th) {
            int msk = 4 >> q;
            float c = cosf(0.5f * th), s = sinf(0.5f * th);
            #pragma unroll
            for (int i = 0; i < 8; ++i) {
                float sg = (i & msk) ? s : -s;   // bit0: e^{-i th/2}, bit1: e^{+i th/2}
                float r = re[i], iM = im[i];
                re[i] = r * c - iM * sg;
                im[i] = r * sg + iM * c;
            }
        };
        rx(0); rx(1); rx(2);
        #pragma unroll
        for (int q = 0; q < 3; ++q) {
            float x = qin[q];
            rzg(q, de * (1.f - 0.5f * x * x));
            hgate(q);
            rzg(q, de * x * x);
            hgate(q);
        }
        rx(0); rx(1); rx(2);
        float e0v = 0.f, e1v = 0.f, e2v = 0.f;
        #pragma unroll
        for (int i = 0; i < 8; ++i) {
            float p = re[i] * re[i] + im[i] * im[i];
            e0v += (i & 4) ? -p : p;
            e1v += (i & 2) ? -p : p;
            e2v += (i & 1) ? -p : p;
        }
        sQout[wave][lane][0] = e0v;
        sQout[wave][lane][1] = e1v;
        sQout[wave][lane][2] = e2v;
    }
    __syncthreads();

    // ---- u = silu([h, agg/100, q_out] @ pW1 + pb1)   (K padded 131 -> 160)
    f32x4 acc2[4] = {z, z, z, z};
    #pragma unroll
    for (int ks = 0; ks < 5; ++ks) {
        const int k0 = ks * 32 + quad * 8;
        bf16x8 a;
        if (k0 < 64) {
            a = cvt8(hrow + k0);
        } else if (k0 < 128) {
            const float* g = grow + (k0 - 64);
            f32x4 u0 = *(const f32x4*)g;
            f32x4 u1 = *(const f32x4*)(g + 4);
            #pragma unroll
            for (int j = 0; j < 4; ++j) { a[j] = (bf16_t)(u0[j] * 0.01f); a[4 + j] = (bf16_t)(u1[j] * 0.01f); }
        } else {
            #pragma unroll
            for (int j = 0; j < 8; ++j) a[j] = (bf16_t)0.f;
            if (k0 == 128) {
                a[0] = (bf16_t)sQout[wave][m][0];
                a[1] = (bf16_t)sQout[wave][m][1];
                a[2] = (bf16_t)sQout[wave][m][2];
            }
        }
        #pragma unroll
        for (int nt = 0; nt < 4; ++nt) {
            bf16x8 b = *(const bf16x8*)&sP1[nt * 16 + m][k0];
            acc2[nt] = mfma16(a, b, acc2[nt]);
        }
    }
    #pragma unroll
    for (int nt = 0; nt < 4; ++nt) {
        #pragma unroll
        for (int rr = 0; rr < 4; ++rr) {
            int row = quad * 4 + rr, col = nt * 16 + m;
            sHid[wave][row][col] = (bf16_t)silu_f(acc2[nt][rr] + spb1[col]);
        }
    }
    __syncthreads();

    // ---- out = h + u @ pW2 + pb2
    f32x4 acc3[4] = {z, z, z, z};
    #pragma unroll
    for (int ks = 0; ks < 2; ++ks) {
        const int k0 = ks * 32 + quad * 8;
        bf16x8 a = *(const bf16x8*)&sHid[wave][m][k0];
        #pragma unroll
        for (int nt = 0; nt < 4; ++nt) {
            bf16x8 b = *(const bf16x8*)&sP2[nt * 16 + m][k0];
            acc3[nt] = mfma16(a, b, acc3[nt]);
        }
    }
    #pragma unroll
    for (int nt = 0; nt < 4; ++nt) {
        #pragma unroll
        for (int rr = 0; rr < 4; ++rr) {
            int row = quad * 4 + rr, col = nt * 16 + m;
            int node = n0 + row;
            if (node < N_NODES) {
                float v = acc3[nt][rr] + spb2[col] + h[(size_t)node * DIM + col];
                out[(size_t)node * DIM + col] = v;
            }
        }
    }
}

extern "C" void kernel_launch(void* const* d_in, const int* in_sizes, int n_in,
                              void* d_out, int out_size, void* d_ws, size_t ws_size,
                              hipStream_t stream)
{
    const float* h   = (const float*)d_in[0];
    const int* ei    = (const int*)d_in[1];
    const float* eW1 = (const float*)d_in[2];
    const float* eb1 = (const float*)d_in[3];
    const float* eW2 = (const float*)d_in[4];
    const float* eb2 = (const float*)d_in[5];
    const float* qW1 = (const float*)d_in[6];
    const float* qb1 = (const float*)d_in[7];
    const float* qW2 = (const float*)d_in[8];
    const float* qb2 = (const float*)d_in[9];
    const float* pW1 = (const float*)d_in[10];
    const float* pb1 = (const float*)d_in[11];
    const float* pW2 = (const float*)d_in[12];
    const float* pb2 = (const float*)d_in[13];
    const float* al  = (const float*)d_in[14];
    const float* be  = (const float*)d_in[15];
    const float* ga  = (const float*)d_in[16];
    const float* de  = (const float*)d_in[17];
    const float* lam = (const float*)d_in[18];

    float* out = (float*)d_out;
    float* mij = out + (size_t)N_NODES * DIM;
    float* agg = (float*)d_ws;

    const int n4 = (N_NODES * HID) / 4;   // 800000 float4s
    zero_kernel<<<(n4 + 255) / 256, 256, 0, stream>>>(agg, n4);
    edge_kernel<<<N_EDGES / 64, 256, 0, stream>>>(h, ei, eW1, eb1, eW2, eb2, mij, agg);
    node_kernel<<<(N_NODES + 63) / 64, 256, 0, stream>>>(h, agg, qW1, qb1, qW2, qb2,
                                                         pW1, pb1, pW2, pb2,
                                                         al, be, ga, de, lam, out);
}